// Round 1
// baseline (344.136 us; speedup 1.0000x reference)
//
#include <hip/hip_runtime.h>
#include <math.h>

// MultiheadAttention: B=2, T=S=2048, C=1024, H=16, D=64
// ws layout (bf16 as ushort): qh[4M] kh[4M] vh[4M] ao[4M] = 32 MB total.

typedef __attribute__((ext_vector_type(4))) float f32x4;
typedef __attribute__((ext_vector_type(8))) __bf16 bf16x8;
typedef __attribute__((ext_vector_type(4))) unsigned int u32x4;
typedef __attribute__((ext_vector_type(4))) unsigned short u16x4;

#define MFMA16(a, b, c) __builtin_amdgcn_mfma_f32_16x16x32_bf16(a, b, c, 0, 0, 0)

static __device__ __forceinline__ unsigned short f2bf(float f) {
    __bf16 h = (__bf16)f;
    return __builtin_bit_cast(unsigned short, h);
}

// ---------------------------------------------------------------------------
// Kernel 1: QKV projections. Y = X @ W^T + b, output bf16 head-split [B,H,L,D].
// Tile 128x128, BK=32, 4 waves (each 64x64 = 4x4 frags of 16x16x32 bf16 MFMA).
// fp32 inputs are converted to bf16 during LDS staging.
// ---------------------------------------------------------------------------
__global__ __launch_bounds__(256, 2)
void proj_qkv_kernel(const float* __restrict__ Xq, const float* __restrict__ Xk,
                     const float* __restrict__ Xv,
                     const float* __restrict__ Wq, const float* __restrict__ Wk,
                     const float* __restrict__ Wv,
                     const float* __restrict__ bq, const float* __restrict__ bk,
                     const float* __restrict__ bv,
                     unsigned short* __restrict__ qh, unsigned short* __restrict__ kh,
                     unsigned short* __restrict__ vh)
{
    const int z = blockIdx.z;
    const float* X    = (z == 0) ? Xq : (z == 1) ? Xk : Xv;
    const float* W    = (z == 0) ? Wq : (z == 1) ? Wk : Wv;
    const float* bias = (z == 0) ? bq : (z == 1) ? bk : bv;
    unsigned short* O = (z == 0) ? qh : (z == 1) ? kh : vh;
    const float scale = (z == 0) ? 0.125f : 1.0f;  // 1/sqrt(64) applied to Q

    __shared__ unsigned short As[128 * 32];
    __shared__ unsigned short Bs[128 * 32];

    const int tid  = threadIdx.x;
    const int lane = tid & 63;
    const int w    = tid >> 6;
    const int l16  = lane & 15;
    const int quad = lane >> 4;
    const int wm   = (w >> 1) * 64;
    const int wn   = (w & 1) * 64;
    const int m0   = blockIdx.y * 128;
    const int n0   = blockIdx.x * 128;

    const int srow = tid >> 3;  // 0..31 (staging row within 32-row group)
    const int sc4  = tid & 7;   // float4 chunk within a 32-col row

    f32x4 acc[4][4];
#pragma unroll
    for (int i = 0; i < 4; i++)
#pragma unroll
        for (int j = 0; j < 4; j++) {
            f32x4 zv = {0.0f, 0.0f, 0.0f, 0.0f};
            acc[i][j] = zv;
        }

    for (int k0 = 0; k0 < 1024; k0 += 32) {
#pragma unroll
        for (int rr = 0; rr < 4; rr++) {
            int row = rr * 32 + srow;
            f32x4 xa = *(const f32x4*)(X + (size_t)(m0 + row) * 1024 + k0 + sc4 * 4);
            f32x4 xb = *(const f32x4*)(W + (size_t)(n0 + row) * 1024 + k0 + sc4 * 4);
            u16x4 ha, hb;
#pragma unroll
            for (int e = 0; e < 4; e++) { ha[e] = f2bf(xa[e]); hb[e] = f2bf(xb[e]); }
            *(u16x4*)(As + row * 32 + sc4 * 4) = ha;
            *(u16x4*)(Bs + row * 32 + sc4 * 4) = hb;
        }
        __syncthreads();

        bf16x8 af[4], bfr[4];
#pragma unroll
        for (int mi = 0; mi < 4; mi++)
            af[mi] = *(const bf16x8*)(As + (wm + mi * 16 + l16) * 32 + quad * 8);
#pragma unroll
        for (int ni = 0; ni < 4; ni++)
            bfr[ni] = *(const bf16x8*)(Bs + (wn + ni * 16 + l16) * 32 + quad * 8);
#pragma unroll
        for (int mi = 0; mi < 4; mi++)
#pragma unroll
            for (int ni = 0; ni < 4; ni++)
                acc[mi][ni] = MFMA16(af[mi], bfr[ni], acc[mi][ni]);
        __syncthreads();
    }

    // Epilogue: C/D layout col=lane&15, row=quad*4+reg (m89/m91 verified).
#pragma unroll
    for (int ni = 0; ni < 4; ni++) {
        int gn = n0 + wn + ni * 16 + l16;
        float bval = bias[gn];
        int h = gn >> 6, d = gn & 63;
#pragma unroll
        for (int mi = 0; mi < 4; mi++) {
#pragma unroll
            for (int r = 0; r < 4; r++) {
                int gm = m0 + wm + mi * 16 + quad * 4 + r;
                int b = gm >> 11, l = gm & 2047;
                float val = (acc[mi][ni][r] + bval) * scale;
                O[(((size_t)(b * 16 + h) * 2048 + l) * 64) + d] = f2bf(val);
            }
        }
    }
}

// ---------------------------------------------------------------------------
// Kernel 2: flash attention. Block = (128 q-rows, one bh). 4 waves, each owns
// 32 q-rows. Q frags in registers (whole kernel), K frags direct from global
// (L1-cached), V staged transposed in LDS, P via LDS round-trip (C->A layout).
// ---------------------------------------------------------------------------
__global__ __launch_bounds__(256, 2)
void attn_kernel(const unsigned short* __restrict__ qh,
                 const unsigned short* __restrict__ kh,
                 const unsigned short* __restrict__ vh,
                 unsigned short* __restrict__ ao)
{
    __shared__ unsigned short Vt[64 * 144];   // V transposed: [d][s], stride 144
    __shared__ unsigned short Ps[128 * 136];  // P tile: [q][s], stride 136

    const int tid  = threadIdx.x;
    const int lane = tid & 63;
    const int w    = tid >> 6;
    const int l16  = lane & 15;
    const int quad = lane >> 4;
    const int qt   = blockIdx.x;  // 0..15
    const int bh   = blockIdx.y;  // 0..31

    const unsigned short* Qb = qh + (size_t)bh * 2048 * 64;
    const unsigned short* Kb = kh + (size_t)bh * 2048 * 64;
    const unsigned short* Vb = vh + (size_t)bh * 2048 * 64;

    // Q fragments: A-layout m=lane&15, k=quad*8+j. Loaded once.
    bf16x8 qf[2][2];
#pragma unroll
    for (int mi = 0; mi < 2; mi++)
#pragma unroll
        for (int ks = 0; ks < 2; ks++)
            qf[mi][ks] = *(const bf16x8*)(Qb +
                (size_t)(qt * 128 + w * 32 + mi * 16 + l16) * 64 + ks * 32 + quad * 8);

    f32x4 o[2][4];
    float mrow[2][4], lrow[2][4];
#pragma unroll
    for (int mi = 0; mi < 2; mi++) {
#pragma unroll
        for (int di = 0; di < 4; di++) {
            f32x4 zv = {0.0f, 0.0f, 0.0f, 0.0f};
            o[mi][di] = zv;
        }
#pragma unroll
        for (int r = 0; r < 4; r++) { mrow[mi][r] = -__builtin_inff(); lrow[mi][r] = 0.0f; }
    }

    for (int s0 = 0; s0 < 2048; s0 += 128) {
        __syncthreads();  // protect Vt reuse (prev iter PV reads done)

        // --- stage V transposed: Vt[d][s], pairs of s packed into one dword ---
#pragma unroll
        for (int r = 0; r < 2; r++) {
            int p  = r * 256 + tid;      // 0..511
            int d0 = (p & 7) * 8;
            int sr = (p >> 3) * 2;       // even s
            const unsigned short* src = Vb + (size_t)(s0 + sr) * 64 + d0;
            u32x4 a  = *(const u32x4*)(src);
            u32x4 b2 = *(const u32x4*)(src + 64);
            unsigned int aw[4] = {a[0], a[1], a[2], a[3]};
            unsigned int bw[4] = {b2[0], b2[1], b2[2], b2[3]};
#pragma unroll
            for (int j = 0; j < 8; j++) {
                int i = (j + (p & 7)) & 7;  // stagger to spread banks
                unsigned int lo = (i & 1) ? (aw[i >> 1] >> 16) : (aw[i >> 1] & 0xffffu);
                unsigned int hi = (i & 1) ? (bw[i >> 1] >> 16) : (bw[i >> 1] & 0xffffu);
                *(unsigned int*)(Vt + (d0 + i) * 144 + sr) = lo | (hi << 16);
            }
        }
        __syncthreads();

        // --- S = Q K^T: B-frag (n=s) read straight from global (L1 hit) ---
        f32x4 sacc[2][8];
#pragma unroll
        for (int mi = 0; mi < 2; mi++)
#pragma unroll
            for (int ni = 0; ni < 8; ni++) {
                f32x4 zv = {0.0f, 0.0f, 0.0f, 0.0f};
                sacc[mi][ni] = zv;
            }
#pragma unroll
        for (int ni = 0; ni < 8; ni++) {
#pragma unroll
            for (int ks = 0; ks < 2; ks++) {
                bf16x8 kf = *(const bf16x8*)(Kb +
                    (size_t)(s0 + ni * 16 + l16) * 64 + ks * 32 + quad * 8);
                sacc[0][ni] = MFMA16(qf[0][ks], kf, sacc[0][ni]);
                sacc[1][ni] = MFMA16(qf[1][ks], kf, sacc[1][ni]);
            }
        }

        // --- online softmax (rows are wave-local: 8 col-frags + 16-lane shfl) ---
#pragma unroll
        for (int mi = 0; mi < 2; mi++) {
#pragma unroll
            for (int r = 0; r < 4; r++) {
                float mx = sacc[mi][0][r];
#pragma unroll
                for (int ni = 1; ni < 8; ni++) mx = fmaxf(mx, sacc[mi][ni][r]);
#pragma unroll
                for (int off = 1; off < 16; off <<= 1)
                    mx = fmaxf(mx, __shfl_xor(mx, off, 64));
                float mnew  = fmaxf(mrow[mi][r], mx);
                float alpha = __expf(mrow[mi][r] - mnew);
                mrow[mi][r] = mnew;
                float sum = 0.0f;
                int prow = w * 32 + mi * 16 + quad * 4 + r;
#pragma unroll
                for (int ni = 0; ni < 8; ni++) {
                    float pv = __expf(sacc[mi][ni][r] - mnew);
                    sum += pv;
                    Ps[prow * 136 + ni * 16 + l16] = f2bf(pv);
                }
#pragma unroll
                for (int off = 1; off < 16; off <<= 1)
                    sum += __shfl_xor(sum, off, 64);
                lrow[mi][r] = lrow[mi][r] * alpha + sum;
#pragma unroll
                for (int di = 0; di < 4; di++) o[mi][di][r] *= alpha;
            }
        }

        // --- O += P V (P rows wave-private; lgkmcnt ordering by compiler) ---
#pragma unroll
        for (int kk = 0; kk < 4; kk++) {
            bf16x8 pf[2];
#pragma unroll
            for (int mi = 0; mi < 2; mi++)
                pf[mi] = *(const bf16x8*)(Ps + (w * 32 + mi * 16 + l16) * 136 + kk * 32 + quad * 8);
#pragma unroll
            for (int di = 0; di < 4; di++) {
                bf16x8 vf = *(const bf16x8*)(Vt + (di * 16 + l16) * 144 + kk * 32 + quad * 8);
#pragma unroll
                for (int mi = 0; mi < 2; mi++)
                    o[mi][di] = MFMA16(pf[mi], vf, o[mi][di]);
            }
        }
    }

    // epilogue: O/l -> bf16 -> ao[b, t, h*64+d]
    const int b = bh >> 4, h = bh & 15;
#pragma unroll
    for (int mi = 0; mi < 2; mi++) {
#pragma unroll
        for (int r = 0; r < 4; r++) {
            float inv = 1.0f / lrow[mi][r];
            int qrow = qt * 128 + w * 32 + mi * 16 + quad * 4 + r;
#pragma unroll
            for (int di = 0; di < 4; di++) {
                float val = o[mi][di][r] * inv;
                ao[(size_t)(b * 2048 + qrow) * 1024 + h * 64 + di * 16 + l16] = f2bf(val);
            }
        }
    }
}

// ---------------------------------------------------------------------------
// Kernel 3: output projection. out = ao(bf16) @ Wo^T + bo, fp32 output.
// ---------------------------------------------------------------------------
__global__ __launch_bounds__(256, 2)
void proj_out_kernel(const unsigned short* __restrict__ A,  // [4096][1024] bf16
                     const float* __restrict__ W,           // [1024][1024]
                     const float* __restrict__ bias,
                     float* __restrict__ out)
{
    __shared__ unsigned short As[128 * 32];
    __shared__ unsigned short Bs[128 * 32];

    const int tid  = threadIdx.x;
    const int lane = tid & 63;
    const int w    = tid >> 6;
    const int l16  = lane & 15;
    const int quad = lane >> 4;
    const int wm   = (w >> 1) * 64;
    const int wn   = (w & 1) * 64;
    const int m0   = blockIdx.y * 128;
    const int n0   = blockIdx.x * 128;

    const int srow = tid >> 3;
    const int sc4  = tid & 7;

    f32x4 acc[4][4];
#pragma unroll
    for (int i = 0; i < 4; i++)
#pragma unroll
        for (int j = 0; j < 4; j++) {
            f32x4 zv = {0.0f, 0.0f, 0.0f, 0.0f};
            acc[i][j] = zv;
        }

    for (int k0 = 0; k0 < 1024; k0 += 32) {
        // stage A (already bf16): 512 16B chunks, 2 per thread
#pragma unroll
        for (int r = 0; r < 2; r++) {
            int j = r * 256 + tid;
            int row = j >> 2, c = j & 3;
            u32x4 v = *(const u32x4*)(A + (size_t)(m0 + row) * 1024 + k0 + c * 8);
            *(u32x4*)(As + row * 32 + c * 8) = v;
        }
        // stage B (Wo fp32 -> bf16)
#pragma unroll
        for (int rr = 0; rr < 4; rr++) {
            int row = rr * 32 + srow;
            f32x4 xb = *(const f32x4*)(W + (size_t)(n0 + row) * 1024 + k0 + sc4 * 4);
            u16x4 hb;
#pragma unroll
            for (int e = 0; e < 4; e++) hb[e] = f2bf(xb[e]);
            *(u16x4*)(Bs + row * 32 + sc4 * 4) = hb;
        }
        __syncthreads();

        bf16x8 af[4], bfr[4];
#pragma unroll
        for (int mi = 0; mi < 4; mi++)
            af[mi] = *(const bf16x8*)(As + (wm + mi * 16 + l16) * 32 + quad * 8);
#pragma unroll
        for (int ni = 0; ni < 4; ni++)
            bfr[ni] = *(const bf16x8*)(Bs + (wn + ni * 16 + l16) * 32 + quad * 8);
#pragma unroll
        for (int mi = 0; mi < 4; mi++)
#pragma unroll
            for (int ni = 0; ni < 4; ni++)
                acc[mi][ni] = MFMA16(af[mi], bfr[ni], acc[mi][ni]);
        __syncthreads();
    }

#pragma unroll
    for (int ni = 0; ni < 4; ni++) {
        int gn = n0 + wn + ni * 16 + l16;
        float bval = bias[gn];
#pragma unroll
        for (int mi = 0; mi < 4; mi++) {
#pragma unroll
            for (int r = 0; r < 4; r++) {
                int gm = m0 + wm + mi * 16 + quad * 4 + r;
                out[(size_t)gm * 1024 + gn] = acc[mi][ni][r] + bval;
            }
        }
    }
}

// ---------------------------------------------------------------------------
extern "C" void kernel_launch(void* const* d_in, const int* in_sizes, int n_in,
                              void* d_out, int out_size, void* d_ws, size_t ws_size,
                              hipStream_t stream)
{
    const float* query = (const float*)d_in[0];
    const float* key   = (const float*)d_in[1];
    const float* value = (const float*)d_in[2];
    const float* Wq    = (const float*)d_in[3];
    const float* bq    = (const float*)d_in[4];
    const float* Wk    = (const float*)d_in[5];
    const float* bk    = (const float*)d_in[6];
    const float* Wv    = (const float*)d_in[7];
    const float* bv    = (const float*)d_in[8];
    const float* Wo    = (const float*)d_in[9];
    const float* bo    = (const float*)d_in[10];
    // d_in[11] = query_chunk_size: evaluation-order hint only, ignored.

    unsigned short* qh = (unsigned short*)d_ws;   // [B,H,T,D] bf16
    unsigned short* kh = qh + 4194304;            // [B,H,S,D]
    unsigned short* vh = kh + 4194304;            // [B,H,S,D]
    unsigned short* ao = vh + 4194304;            // [B,T,C]  (needs 32 MB ws total)
    float* out = (float*)d_out;

    proj_qkv_kernel<<<dim3(8, 32, 3), 256, 0, stream>>>(
        query, key, value, Wq, Wk, Wv, bq, bk, bv, qh, kh, vh);
    attn_kernel<<<dim3(16, 32), 256, 0, stream>>>(qh, kh, vh, ao);
    proj_out_kernel<<<dim3(8, 32), 256, 0, stream>>>(ao, Wo, bo, out);
}